// Round 2
// baseline (781.680 us; speedup 1.0000x reference)
//
#include <hip/hip_runtime.h>
#include <hip/hip_bf16.h>

#define DM   1024
#define HEADS 16
#define DH    64
#define SEQ  2048
#define BATCH   2

typedef __attribute__((ext_vector_type(8))) short short8;
typedef __attribute__((ext_vector_type(4))) float floatx4;

__device__ inline short f2b(float f) {
    union { float f; unsigned u; } v; v.f = f;
    unsigned r = v.u + 0x7FFFu + ((v.u >> 16) & 1u);
    return (short)(r >> 16);
}

// out[m][n] = sum_k x[m][k]*W[n][k] + bias[n]; out bf16 in head layout.
// vt_layout==0: out[((b*H+h)*S+s)*64+dh]   (Q,K)
// vt_layout==1: out[((b*H+h)*64+dh)*S+s]   (V transposed)
__global__ __launch_bounds__(256) void proj_qkv(const float* __restrict__ x,
        const float* __restrict__ W, const float* __restrict__ bias,
        short* __restrict__ out, int vt_layout)
{
    const int mt = blockIdx.x;      // 0..63
    const int h  = blockIdx.y;      // 0..15 (head == 64-wide n-tile)
    const int wave = threadIdx.x >> 6, lane = threadIdx.x & 63;
    const int l16 = lane & 15, quad = lane >> 4;
    const int arow = mt * 64 + wave * 16 + l16;

    floatx4 acc[4];
#pragma unroll
    for (int nt = 0; nt < 4; ++nt) acc[nt] = (floatx4){0.f, 0.f, 0.f, 0.f};

#pragma unroll 1
    for (int ks = 0; ks < 32; ++ks) {
        const int k0 = ks * 32 + quad * 8;
        const float* ap = x + (size_t)arow * DM + k0;
        short8 a;
#pragma unroll
        for (int j = 0; j < 8; ++j) a[j] = f2b(ap[j]);
#pragma unroll
        for (int nt = 0; nt < 4; ++nt) {
            const float* bp = W + (size_t)(h * 64 + nt * 16 + l16) * DM + k0;
            short8 b;
#pragma unroll
            for (int j = 0; j < 8; ++j) b[j] = f2b(bp[j]);
            acc[nt] = __builtin_amdgcn_mfma_f32_16x16x32_bf16(a, b, acc[nt], 0, 0, 0);
        }
    }

    const int tokbase = mt * 64 + wave * 16 + quad * 4;
#pragma unroll
    for (int nt = 0; nt < 4; ++nt) {
        const int dh = nt * 16 + l16;
        const float bv = bias[h * 64 + dh];
#pragma unroll
        for (int r = 0; r < 4; ++r) {
            const int tok = tokbase + r;
            const int bb = tok >> 11, s = tok & (SEQ - 1);
            const float val = acc[nt][r] + bv;
            size_t idx = vt_layout
                ? (((size_t)(bb * HEADS + h)) * DH + dh) * SEQ + s
                : (((size_t)(bb * HEADS + h)) * SEQ + s) * DH + dh;
            out[idx] = f2b(val);
        }
    }
}

// Flash attention: q,k [b,h,s,dh] bf16; vt [b,h,dh,s] bf16; ctx [b,s,h*dh] bf16.
__global__ __launch_bounds__(256) void attn_kernel(const short* __restrict__ q,
        const short* __restrict__ k, const short* __restrict__ vt,
        const float* __restrict__ mask, short* __restrict__ ctx)
{
    const int qtile = blockIdx.x;   // 0..31
    const int bh    = blockIdx.y;   // 0..31
    const int bidx  = bh >> 4;
    const int wave = threadIdx.x >> 6, lane = threadIdx.x & 63;
    const int l16 = lane & 15, quad = lane >> 4;

    __shared__ short k_lds[64][72];        // [key][dh], pad 8
    __shared__ short v_lds[64][72];        // [dh][key], pad 8
    __shared__ short p_lds[4][16][72];     // per-wave P round-trip

    // Q A-fragment: A[m=l16][k=quad*8+j]; Dh=64 -> 2 k-steps of 32.
    const int qrow = qtile * 64 + wave * 16 + l16;
    const short* qbase = q + ((size_t)bh * SEQ + qrow) * DH;
    short8 a_q[2];
#pragma unroll
    for (int ks = 0; ks < 2; ++ks)
        a_q[ks] = *(const short8*)(qbase + ks * 32 + quad * 8);

    float m_r[4], l_r[4];
    floatx4 o[4];
#pragma unroll
    for (int r = 0; r < 4; ++r) { m_r[r] = -1e30f; l_r[r] = 0.f; }
#pragma unroll
    for (int d = 0; d < 4; ++d) o[d] = (floatx4){0.f, 0.f, 0.f, 0.f};

    const float scale = 0.125f;  // 1/sqrt(64)

    for (int kt = 0; kt < SEQ / 64; ++kt) {
        __syncthreads();
        {   // stage K and V tiles: 64x64 shorts each; 256 thr -> 16 shorts/thr/array
            const int t = threadIdx.x;
            const int row = t >> 2;           // 0..63
            const int off = (t & 3) * 16;     // 0,16,32,48 (each thread: 16 shorts)
            const short* kp = k + ((size_t)bh * SEQ + kt * 64 + row) * DH + off;
            *(short8*)&k_lds[row][off]     = *(const short8*)kp;
            *(short8*)&k_lds[row][off + 8] = *(const short8*)(kp + 8);
            const short* vp = vt + ((size_t)bh * DH + row) * SEQ + kt * 64 + off;
            *(short8*)&v_lds[row][off]     = *(const short8*)vp;
            *(short8*)&v_lds[row][off + 8] = *(const short8*)(vp + 8);
        }
        __syncthreads();

        // S = Q K^T * scale + mask
        float s_nt[4][4];
#pragma unroll
        for (int nt = 0; nt < 4; ++nt) {
            floatx4 acc = (floatx4){0.f, 0.f, 0.f, 0.f};
#pragma unroll
            for (int ks = 0; ks < 2; ++ks) {
                short8 b = *(const short8*)&k_lds[nt * 16 + l16][ks * 32 + quad * 8];
                acc = __builtin_amdgcn_mfma_f32_16x16x32_bf16(a_q[ks], b, acc, 0, 0, 0);
            }
            const int key = kt * 64 + nt * 16 + l16;
            const float mk = mask[bidx * SEQ + key];
            const float madd = (1.f - mk) * (-100000.f);
#pragma unroll
            for (int r = 0; r < 4; ++r) s_nt[nt][r] = acc[r] * scale + madd;
        }

        // online softmax per row r (row = quad*4+r, cols on l16 across 4 nt)
#pragma unroll
        for (int r = 0; r < 4; ++r) {
            float tm = fmaxf(fmaxf(s_nt[0][r], s_nt[1][r]), fmaxf(s_nt[2][r], s_nt[3][r]));
#pragma unroll
            for (int off = 1; off < 16; off <<= 1) tm = fmaxf(tm, __shfl_xor(tm, off));
            const float nm = fmaxf(m_r[r], tm);
            const float alpha = __expf(m_r[r] - nm);
            float ps = 0.f;
#pragma unroll
            for (int nt = 0; nt < 4; ++nt) {
                const float p = __expf(s_nt[nt][r] - nm);
                s_nt[nt][r] = p;
                ps += p;
            }
#pragma unroll
            for (int off = 1; off < 16; off <<= 1) ps += __shfl_xor(ps, off);
            l_r[r] = l_r[r] * alpha + ps;
            m_r[r] = nm;
#pragma unroll
            for (int d = 0; d < 4; ++d) o[d][r] *= alpha;
#pragma unroll
            for (int nt = 0; nt < 4; ++nt)
                p_lds[wave][quad * 4 + r][nt * 16 + l16] = f2b(s_nt[nt][r]);
        }

        // O += P V  (P via LDS round-trip to A-layout; V from v_lds[dh][key])
#pragma unroll
        for (int ks2 = 0; ks2 < 2; ++ks2) {
            short8 ap = *(const short8*)&p_lds[wave][l16][ks2 * 32 + quad * 8];
#pragma unroll
            for (int d = 0; d < 4; ++d) {
                short8 bv = *(const short8*)&v_lds[d * 16 + l16][ks2 * 32 + quad * 8];
                o[d] = __builtin_amdgcn_mfma_f32_16x16x32_bf16(ap, bv, o[d], 0, 0, 0);
            }
        }
    }

    // epilogue: ctx[b][s][h*64+dh] = o / l
    const int h = bh & 15, bb = bh >> 4;
    const int srow = qtile * 64 + wave * 16 + quad * 4;
#pragma unroll
    for (int d = 0; d < 4; ++d) {
        const int dh = d * 16 + l16;
#pragma unroll
        for (int r = 0; r < 4; ++r) {
            const float val = o[d][r] / l_r[r];
            ctx[((size_t)(bb * SEQ + srow + r)) * DM + h * 64 + dh] = f2b(val);
        }
    }
}

// y[m][n] = sum_k ctx[m][k]*Wo[n][k] + bo[n] + xin[m][n]   (fp32 out, into d_out)
__global__ __launch_bounds__(256) void proj_o(const short* __restrict__ ctx,
        const float* __restrict__ W, const float* __restrict__ bias,
        const float* __restrict__ xin, float* __restrict__ y)
{
    const int mt = blockIdx.x, ntile = blockIdx.y;
    const int wave = threadIdx.x >> 6, lane = threadIdx.x & 63;
    const int l16 = lane & 15, quad = lane >> 4;
    const int arow = mt * 64 + wave * 16 + l16;

    floatx4 acc[4];
#pragma unroll
    for (int nt = 0; nt < 4; ++nt) acc[nt] = (floatx4){0.f, 0.f, 0.f, 0.f};

#pragma unroll 1
    for (int ks = 0; ks < 32; ++ks) {
        const int k0 = ks * 32 + quad * 8;
        short8 a = *(const short8*)(ctx + (size_t)arow * DM + k0);
#pragma unroll
        for (int nt = 0; nt < 4; ++nt) {
            const float* bp = W + (size_t)(ntile * 64 + nt * 16 + l16) * DM + k0;
            short8 b;
#pragma unroll
            for (int j = 0; j < 8; ++j) b[j] = f2b(bp[j]);
            acc[nt] = __builtin_amdgcn_mfma_f32_16x16x32_bf16(a, b, acc[nt], 0, 0, 0);
        }
    }

    const int tokbase = mt * 64 + wave * 16 + quad * 4;
#pragma unroll
    for (int nt = 0; nt < 4; ++nt) {
        const int ncol = ntile * 64 + nt * 16 + l16;
        const float bv = bias[ncol];
#pragma unroll
        for (int r = 0; r < 4; ++r) {
            const size_t idx = (size_t)(tokbase + r) * DM + ncol;
            y[idx] = acc[nt][r] + bv + xin[idx];
        }
    }
}

// In-place LayerNorm over rows of y (each thread reads/writes only its own 4 elems)
__global__ __launch_bounds__(256) void ln_kernel(float* __restrict__ y,
        const float* __restrict__ gamma, const float* __restrict__ beta)
{
    const int row = blockIdx.x;
    const int t = threadIdx.x;
    const int wave = t >> 6, lane = t & 63;
    const floatx4 v = ((const floatx4*)(y + (size_t)row * DM))[t];
    float s  = v.x + v.y + v.z + v.w;
    float q2 = v.x * v.x + v.y * v.y + v.z * v.z + v.w * v.w;
#pragma unroll
    for (int off = 1; off < 64; off <<= 1) {
        s  += __shfl_xor(s, off);
        q2 += __shfl_xor(q2, off);
    }
    __shared__ float rs[4], rq[4];
    if (lane == 0) { rs[wave] = s; rq[wave] = q2; }
    __syncthreads();
    const float S  = rs[0] + rs[1] + rs[2] + rs[3];
    const float Q2 = rq[0] + rq[1] + rq[2] + rq[3];
    const float mu = S * (1.f / DM);
    float var = Q2 * (1.f / DM) - mu * mu;
    var = fmaxf(var, 0.f);
    const float rstd = rsqrtf(var + 1e-12f);
    const floatx4 g = ((const floatx4*)gamma)[t];
    const floatx4 bt = ((const floatx4*)beta)[t];
    floatx4 o;
    o.x = (v.x - mu) * rstd * g.x + bt.x;
    o.y = (v.y - mu) * rstd * g.y + bt.y;
    o.z = (v.z - mu) * rstd * g.z + bt.z;
    o.w = (v.w - mu) * rstd * g.w + bt.w;
    ((floatx4*)(y + (size_t)row * DM))[t] = o;
}

extern "C" void kernel_launch(void* const* d_in, const int* in_sizes, int n_in,
                              void* d_out, int out_size, void* d_ws, size_t ws_size,
                              hipStream_t stream) {
    const float* x     = (const float*)d_in[0];
    const float* mask  = (const float*)d_in[1];
    const float* Wq    = (const float*)d_in[2];
    const float* bq    = (const float*)d_in[3];
    const float* Wk    = (const float*)d_in[4];
    const float* bk    = (const float*)d_in[5];
    const float* Wv    = (const float*)d_in[6];
    const float* bv    = (const float*)d_in[7];
    const float* Wo    = (const float*)d_in[8];
    const float* bo    = (const float*)d_in[9];
    const float* gamma = (const float*)d_in[10];
    const float* beta  = (const float*)d_in[11];
    float* out = (float*)d_out;

    const size_t NTOK = (size_t)BATCH * SEQ * DM;  // 4M elements
    short* qw   = (short*)d_ws;
    short* kw   = qw  + NTOK;
    short* vtw  = kw  + NTOK;
    short* ctxw = vtw + NTOK;

    dim3 gproj(64, 16, 1), blk(256);
    proj_qkv<<<gproj, blk, 0, stream>>>(x, Wq, bq, qw, 0);
    proj_qkv<<<gproj, blk, 0, stream>>>(x, Wk, bk, kw, 0);
    proj_qkv<<<gproj, blk, 0, stream>>>(x, Wv, bv, vtw, 1);
    attn_kernel<<<dim3(SEQ / 64, BATCH * HEADS), blk, 0, stream>>>(qw, kw, vtw, mask, ctxw);
    proj_o<<<gproj, blk, 0, stream>>>(ctxw, Wo, bo, x, out);
    ln_kernel<<<BATCH * SEQ, blk, 0, stream>>>(out, gamma, beta);
}

// Round 4
// 296.619 us; speedup vs baseline: 2.6353x; 2.6353x over previous
//
#include <hip/hip_runtime.h>
#include <hip/hip_bf16.h>

#define DM   1024
#define HEADS 16
#define DH    64
#define SEQ  2048
#define BATCH   2

typedef __attribute__((ext_vector_type(8))) short short8;
typedef __attribute__((ext_vector_type(4))) short bf16x4;
typedef __attribute__((ext_vector_type(4))) float floatx4;

__device__ __forceinline__ short f2b(float f) {
    union { float f; unsigned u; } v; v.f = f;
    unsigned r = v.u + 0x7FFFu + ((v.u >> 16) & 1u);
    return (short)(r >> 16);
}

__device__ __forceinline__ void async_copy16(const short* gsrc, short* ldst) {
    __builtin_amdgcn_global_load_lds(
        (const __attribute__((address_space(1))) void*)gsrc,
        (__attribute__((address_space(3))) void*)ldst,
        16, 0, 0);
}

// fp32 -> bf16 copy, 4 elems/thread
__global__ __launch_bounds__(256) void cvt_bf16(const float* __restrict__ src,
                                                short* __restrict__ dst, int n4) {
    int i = blockIdx.x * 256 + threadIdx.x;
    if (i < n4) {
        floatx4 v = ((const floatx4*)src)[i];
        bf16x4 o;
        o.x = f2b(v.x); o.y = f2b(v.y); o.z = f2b(v.z); o.w = f2b(v.w);
        ((bf16x4*)dst)[i] = o;
    }
}

// Fused QKV GEMM: A=xb [4096x1024] bf16, B=wqkv [3072x1024] bf16 (rows 0-1023 Wq,
// 1024-2047 Wk, 2048-3071 Wv). 128x128 tile, BK=32, m97 structure.
// Epilogue: +bias, bf16, Q/K/V all in [b,h,s,dh] natural layout.
__global__ __launch_bounds__(256) void gemm_qkv(const short* __restrict__ A,
        const short* __restrict__ B,
        const float* __restrict__ bq, const float* __restrict__ bk,
        const float* __restrict__ bv,
        short* __restrict__ qw, short* __restrict__ kw, short* __restrict__ vw)
{
    __shared__ short As[128 * 32];
    __shared__ short Bs[128 * 32];
    const int m0 = blockIdx.x * 128, n0 = blockIdx.y * 128;
    const int w = threadIdx.x >> 6, lane = threadIdx.x & 63;
    const int l16 = lane & 15, quad = lane >> 4;
    const int wm = w >> 1, wn = w & 1;
    const int lr = lane >> 2, lc = (lane & 3) * 8;

    floatx4 acc[4][4];
#pragma unroll
    for (int i = 0; i < 4; ++i)
#pragma unroll
        for (int j = 0; j < 4; ++j) acc[i][j] = (floatx4){0.f, 0.f, 0.f, 0.f};

    for (int kt = 0; kt < DM / 32; ++kt) {
        const int k0 = kt * 32;
        __syncthreads();
        async_copy16(A + (size_t)(m0 + w * 32 + lr) * DM + k0 + lc,      &As[w * 1024]);
        async_copy16(A + (size_t)(m0 + w * 32 + 16 + lr) * DM + k0 + lc, &As[w * 1024 + 512]);
        async_copy16(B + (size_t)(n0 + w * 32 + lr) * DM + k0 + lc,      &Bs[w * 1024]);
        async_copy16(B + (size_t)(n0 + w * 32 + 16 + lr) * DM + k0 + lc, &Bs[w * 1024 + 512]);
        __syncthreads();

        short8 af[4], bf[4];
#pragma unroll
        for (int i = 0; i < 4; ++i)
            af[i] = *(const short8*)&As[(wm * 64 + i * 16 + l16) * 32 + quad * 8];
#pragma unroll
        for (int j = 0; j < 4; ++j)
            bf[j] = *(const short8*)&Bs[(wn * 64 + j * 16 + l16) * 32 + quad * 8];
#pragma unroll
        for (int i = 0; i < 4; ++i)
#pragma unroll
            for (int j = 0; j < 4; ++j)
                acc[i][j] = __builtin_amdgcn_mfma_f32_16x16x32_bf16(af[i], bf[j], acc[i][j], 0, 0, 0);
    }

    const int m_base = m0 + wm * 64 + quad * 4;
#pragma unroll
    for (int j = 0; j < 4; ++j) {
        const int nb = n0 + wn * 64 + j * 16;       // 16-aligned, uniform per fragment
        const int t = nb >> 10;
        const int nn = (nb & 1023) + l16;
        const int h = nn >> 6, dh = nn & 63;
        const float* bias = (t == 0) ? bq : (t == 1) ? bk : bv;
        short* dst = (t == 0) ? qw : (t == 1) ? kw : vw;
        const float bvv = bias[nn];
#pragma unroll
        for (int i = 0; i < 4; ++i)
#pragma unroll
            for (int r = 0; r < 4; ++r) {
                const int m = m_base + i * 16 + r;
                const int b = m >> 11, s = m & (SEQ - 1);
                dst[(((size_t)(b * HEADS + h)) * SEQ + s) * DH + dh] = f2b(acc[i][j][r] + bvv);
            }
    }
}

// v [b,h,s,dh] -> vt [b,h,dh,s], 64x64 LDS tiles
__global__ __launch_bounds__(256) void transpose_v(const short* __restrict__ v,
                                                   short* __restrict__ vt)
{
    __shared__ short tl[64][72];
    const int st = blockIdx.x;   // s-tile
    const int bh = blockIdx.y;
    const int t = threadIdx.x;
    const int row = t >> 2, off = (t & 3) * 16;
    const short* vp = v + ((size_t)bh * SEQ + st * 64 + row) * DH + off;
    *(short8*)&tl[row][off]     = *(const short8*)vp;
    *(short8*)&tl[row][off + 8] = *(const short8*)(vp + 8);
    __syncthreads();
    short8 o0, o1;
#pragma unroll
    for (int j = 0; j < 8; ++j) { o0[j] = tl[off + j][row]; o1[j] = tl[off + 8 + j][row]; }
    short* op = vt + ((size_t)bh * DH + row) * SEQ + st * 64 + off;
    *(short8*)op = o0;
    *(short8*)(op + 8) = o1;
}

// Flash attention: q,k [b,h,s,dh] bf16; vt [b,h,dh,s] bf16; ctx [b,s,h*dh] bf16.
__global__ __launch_bounds__(256) void attn_kernel(const short* __restrict__ q,
        const short* __restrict__ k, const short* __restrict__ vt,
        const float* __restrict__ mask, short* __restrict__ ctx)
{
    const int qtile = blockIdx.x;
    const int bh    = blockIdx.y;
    const int bidx  = bh >> 4;
    const int wave = threadIdx.x >> 6, lane = threadIdx.x & 63;
    const int l16 = lane & 15, quad = lane >> 4;

    __shared__ short k_lds[64][72];
    __shared__ short v_lds[64][72];
    __shared__ short p_lds[4][16][72];

    const int qrow = qtile * 64 + wave * 16 + l16;
    const short* qbase = q + ((size_t)bh * SEQ + qrow) * DH;
    short8 a_q[2];
#pragma unroll
    for (int ks = 0; ks < 2; ++ks)
        a_q[ks] = *(const short8*)(qbase + ks * 32 + quad * 8);

    float m_r[4], l_r[4];
    floatx4 o[4];
#pragma unroll
    for (int r = 0; r < 4; ++r) { m_r[r] = -1e30f; l_r[r] = 0.f; }
#pragma unroll
    for (int d = 0; d < 4; ++d) o[d] = (floatx4){0.f, 0.f, 0.f, 0.f};

    const float scale = 0.125f;

    for (int kt = 0; kt < SEQ / 64; ++kt) {
        __syncthreads();
        {
            const int t = threadIdx.x;
            const int row = t >> 2;
            const int off = (t & 3) * 16;
            const short* kp = k + ((size_t)bh * SEQ + kt * 64 + row) * DH + off;
            *(short8*)&k_lds[row][off]     = *(const short8*)kp;
            *(short8*)&k_lds[row][off + 8] = *(const short8*)(kp + 8);
            const short* vp = vt + ((size_t)bh * DH + row) * SEQ + kt * 64 + off;
            *(short8*)&v_lds[row][off]     = *(const short8*)vp;
            *(short8*)&v_lds[row][off + 8] = *(const short8*)(vp + 8);
        }
        __syncthreads();

        float s_nt[4][4];
#pragma unroll
        for (int nt = 0; nt < 4; ++nt) {
            floatx4 acc = (floatx4){0.f, 0.f, 0.f, 0.f};
#pragma unroll
            for (int ks = 0; ks < 2; ++ks) {
                short8 b = *(const short8*)&k_lds[nt * 16 + l16][ks * 32 + quad * 8];
                acc = __builtin_amdgcn_mfma_f32_16x16x32_bf16(a_q[ks], b, acc, 0, 0, 0);
            }
            const int key = kt * 64 + nt * 16 + l16;
            const float mk = mask[bidx * SEQ + key];
            const float madd = (1.f - mk) * (-100000.f);
#pragma unroll
            for (int r = 0; r < 4; ++r) s_nt[nt][r] = acc[r] * scale + madd;
        }

#pragma unroll
        for (int r = 0; r < 4; ++r) {
            float tm = fmaxf(fmaxf(s_nt[0][r], s_nt[1][r]), fmaxf(s_nt[2][r], s_nt[3][r]));
#pragma unroll
            for (int off = 1; off < 16; off <<= 1) tm = fmaxf(tm, __shfl_xor(tm, off));
            const float nm = fmaxf(m_r[r], tm);
            const float alpha = __expf(m_r[r] - nm);
            float ps = 0.f;
#pragma unroll
            for (int nt = 0; nt < 4; ++nt) {
                const float p = __expf(s_nt[nt][r] - nm);
                s_nt[nt][r] = p;
                ps += p;
            }
#pragma unroll
            for (int off = 1; off < 16; off <<= 1) ps += __shfl_xor(ps, off);
            l_r[r] = l_r[r] * alpha + ps;
            m_r[r] = nm;
#pragma unroll
            for (int d = 0; d < 4; ++d) o[d][r] *= alpha;
#pragma unroll
            for (int nt = 0; nt < 4; ++nt)
                p_lds[wave][quad * 4 + r][nt * 16 + l16] = f2b(s_nt[nt][r]);
        }

#pragma unroll
        for (int ks2 = 0; ks2 < 2; ++ks2) {
            short8 ap = *(const short8*)&p_lds[wave][l16][ks2 * 32 + quad * 8];
#pragma unroll
            for (int d = 0; d < 4; ++d) {
                short8 bv = *(const short8*)&v_lds[d * 16 + l16][ks2 * 32 + quad * 8];
                o[d] = __builtin_amdgcn_mfma_f32_16x16x32_bf16(ap, bv, o[d], 0, 0, 0);
            }
        }
    }

    const int h = bh & 15, bb = bh >> 4;
    const int srow = qtile * 64 + wave * 16 + quad * 4;
#pragma unroll
    for (int d = 0; d < 4; ++d) {
        const int dh = d * 16 + l16;
#pragma unroll
        for (int r = 0; r < 4; ++r) {
            const float val = o[d][r] / l_r[r];
            ctx[((size_t)(bb * SEQ + srow + r)) * DM + h * 64 + dh] = f2b(val);
        }
    }
}

// Output GEMM: A=ctx bf16 [4096x1024], B=wob bf16 [1024x1024].
// Epilogue: + bo + residual x (fp32), fp32 out.
__global__ __launch_bounds__(256) void gemm_o(const short* __restrict__ A,
        const short* __restrict__ B, const float* __restrict__ bo,
        const float* __restrict__ xin, float* __restrict__ out)
{
    __shared__ short As[128 * 32];
    __shared__ short Bs[128 * 32];
    const int m0 = blockIdx.x * 128, n0 = blockIdx.y * 128;
    const int w = threadIdx.x >> 6, lane = threadIdx.x & 63;
    const int l16 = lane & 15, quad = lane >> 4;
    const int wm = w >> 1, wn = w & 1;
    const int lr = lane >> 2, lc = (lane & 3) * 8;

    floatx4 acc[4][4];
#pragma unroll
    for (int i = 0; i < 4; ++i)
#pragma unroll
        for (int j = 0; j < 4; ++j) acc[i][j] = (floatx4){0.f, 0.f, 0.f, 0.f};

    for (int kt = 0; kt < DM / 32; ++kt) {
        const int k0 = kt * 32;
        __syncthreads();
        async_copy16(A + (size_t)(m0 + w * 32 + lr) * DM + k0 + lc,      &As[w * 1024]);
        async_copy16(A + (size_t)(m0 + w * 32 + 16 + lr) * DM + k0 + lc, &As[w * 1024 + 512]);
        async_copy16(B + (size_t)(n0 + w * 32 + lr) * DM + k0 + lc,      &Bs[w * 1024]);
        async_copy16(B + (size_t)(n0 + w * 32 + 16 + lr) * DM + k0 + lc, &Bs[w * 1024 + 512]);
        __syncthreads();

        short8 af[4], bf[4];
#pragma unroll
        for (int i = 0; i < 4; ++i)
            af[i] = *(const short8*)&As[(wm * 64 + i * 16 + l16) * 32 + quad * 8];
#pragma unroll
        for (int j = 0; j < 4; ++j)
            bf[j] = *(const short8*)&Bs[(wn * 64 + j * 16 + l16) * 32 + quad * 8];
#pragma unroll
        for (int i = 0; i < 4; ++i)
#pragma unroll
            for (int j = 0; j < 4; ++j)
                acc[i][j] = __builtin_amdgcn_mfma_f32_16x16x32_bf16(af[i], bf[j], acc[i][j], 0, 0, 0);
    }

    const int m_base = m0 + wm * 64 + quad * 4;
#pragma unroll
    for (int j = 0; j < 4; ++j) {
        const int n = n0 + wn * 64 + j * 16 + l16;
        const float bvv = bo[n];
#pragma unroll
        for (int i = 0; i < 4; ++i)
#pragma unroll
            for (int r = 0; r < 4; ++r) {
                const int m = m_base + i * 16 + r;
                const size_t idx = (size_t)m * DM + n;
                out[idx] = acc[i][j][r] + bvv + xin[idx];
            }
    }
}

__global__ __launch_bounds__(256) void ln_kernel(float* __restrict__ y,
        const float* __restrict__ gamma, const float* __restrict__ beta)
{
    const int row = blockIdx.x;
    const int t = threadIdx.x;
    const int wave = t >> 6, lane = t & 63;
    const floatx4 v = ((const floatx4*)(y + (size_t)row * DM))[t];
    float s  = v.x + v.y + v.z + v.w;
    float q2 = v.x * v.x + v.y * v.y + v.z * v.z + v.w * v.w;
#pragma unroll
    for (int off = 1; off < 64; off <<= 1) {
        s  += __shfl_xor(s, off);
        q2 += __shfl_xor(q2, off);
    }
    __shared__ float rs[4], rq[4];
    if (lane == 0) { rs[wave] = s; rq[wave] = q2; }
    __syncthreads();
    const float S  = rs[0] + rs[1] + rs[2] + rs[3];
    const float Q2 = rq[0] + rq[1] + rq[2] + rq[3];
    const float mu = S * (1.f / DM);
    float var = Q2 * (1.f / DM) - mu * mu;
    var = fmaxf(var, 0.f);
    const float rstd = rsqrtf(var + 1e-12f);
    const floatx4 g = ((const floatx4*)gamma)[t];
    const floatx4 bt = ((const floatx4*)beta)[t];
    floatx4 o;
    o.x = (v.x - mu) * rstd * g.x + bt.x;
    o.y = (v.y - mu) * rstd * g.y + bt.y;
    o.z = (v.z - mu) * rstd * g.z + bt.z;
    o.w = (v.w - mu) * rstd * g.w + bt.w;
    ((floatx4*)(y + (size_t)row * DM))[t] = o;
}

extern "C" void kernel_launch(void* const* d_in, const int* in_sizes, int n_in,
                              void* d_out, int out_size, void* d_ws, size_t ws_size,
                              hipStream_t stream) {
    const float* x     = (const float*)d_in[0];
    const float* mask  = (const float*)d_in[1];
    const float* Wq    = (const float*)d_in[2];
    const float* bq    = (const float*)d_in[3];
    const float* Wk    = (const float*)d_in[4];
    const float* bk    = (const float*)d_in[5];
    const float* Wv    = (const float*)d_in[6];
    const float* bv    = (const float*)d_in[7];
    const float* Wo    = (const float*)d_in[8];
    const float* bo    = (const float*)d_in[9];
    const float* gamma = (const float*)d_in[10];
    const float* beta  = (const float*)d_in[11];
    float* out = (float*)d_out;

    const size_t NTOK = (size_t)BATCH * SEQ * DM;       // 4M
    const size_t WSZ  = (size_t)DM * DM;                // 1M
    short* xb   = (short*)d_ws;          // 4M
    short* wqkv = xb + NTOK;             // 3M
    short* wob  = wqkv + 3 * WSZ;        // 1M
    short* qw   = wob + WSZ;             // 4M
    short* kw   = qw + NTOK;             // 4M
    short* vw   = kw + NTOK;             // 4M (aliased as ctx after transpose)
    short* vtw  = vw + NTOK;             // 4M   -> total 24M shorts = 48 MB
    short* ctxw = vw;

    dim3 blk(256);
    cvt_bf16<<<dim3(NTOK / 1024), blk, 0, stream>>>(x,  xb, NTOK / 4);
    cvt_bf16<<<dim3(WSZ / 1024),  blk, 0, stream>>>(Wq, wqkv,           WSZ / 4);
    cvt_bf16<<<dim3(WSZ / 1024),  blk, 0, stream>>>(Wk, wqkv + WSZ,     WSZ / 4);
    cvt_bf16<<<dim3(WSZ / 1024),  blk, 0, stream>>>(Wv, wqkv + 2 * WSZ, WSZ / 4);
    cvt_bf16<<<dim3(WSZ / 1024),  blk, 0, stream>>>(Wo, wob,            WSZ / 4);

    gemm_qkv<<<dim3(32, 24), blk, 0, stream>>>(xb, wqkv, bq, bk, bv, qw, kw, vw);
    transpose_v<<<dim3(SEQ / 64, BATCH * HEADS), blk, 0, stream>>>(vw, vtw);
    attn_kernel<<<dim3(SEQ / 64, BATCH * HEADS), blk, 0, stream>>>(qw, kw, vtw, mask, ctxw);
    gemm_o<<<dim3(32, 8), blk, 0, stream>>>(ctxw, wob, bo, x, out);
    ln_kernel<<<BATCH * SEQ, blk, 0, stream>>>(out, gamma, beta);
}

// Round 5
// 245.829 us; speedup vs baseline: 3.1798x; 1.2066x over previous
//
#include <hip/hip_runtime.h>
#include <hip/hip_bf16.h>

#define DM   1024
#define HEADS 16
#define DH    64
#define SEQ  2048
#define BATCH   2

typedef __attribute__((ext_vector_type(8))) short short8;
typedef __attribute__((ext_vector_type(4))) short bf16x4;
typedef __attribute__((ext_vector_type(4))) float floatx4;

__device__ __forceinline__ short f2b(float f) {
    union { float f; unsigned u; } v; v.f = f;
    unsigned r = v.u + 0x7FFFu + ((v.u >> 16) & 1u);
    return (short)(r >> 16);
}

__device__ __forceinline__ void async_copy16(const short* gsrc, short* ldst) {
    __builtin_amdgcn_global_load_lds(
        (const __attribute__((address_space(1))) void*)gsrc,
        (__attribute__((address_space(3))) void*)ldst,
        16, 0, 0);
}

// Fused fp32->bf16 conversion of x, Wq, Wk, Wv, Wo in one launch.
// Blocks: [0,4096) x ; [4096,5120) Wq ; [5120,6144) Wk ; [6144,7168) Wv ; [7168,8192) Wo
__global__ __launch_bounds__(256) void cvt_all(const float* __restrict__ x,
        const float* __restrict__ wq, const float* __restrict__ wk,
        const float* __restrict__ wv, const float* __restrict__ wo,
        short* __restrict__ xb, short* __restrict__ wqkv, short* __restrict__ wob)
{
    const int b = blockIdx.x;
    const float* src; short* dst; int idx;
    if (b < 4096)      { src = x;  dst = xb;                idx = b; }
    else if (b < 5120) { src = wq; dst = wqkv;              idx = b - 4096; }
    else if (b < 6144) { src = wk; dst = wqkv + (1 << 20);  idx = b - 5120; }
    else if (b < 7168) { src = wv; dst = wqkv + (2 << 20);  idx = b - 6144; }
    else               { src = wo; dst = wob;               idx = b - 7168; }
    const int i = idx * 256 + threadIdx.x;
    floatx4 v = ((const floatx4*)src)[i];
    bf16x4 o;
    o.x = f2b(v.x); o.y = f2b(v.y); o.z = f2b(v.z); o.w = f2b(v.w);
    ((bf16x4*)dst)[i] = o;
}

// Fused QKV GEMM (m97 structure, 128x128 tile, BK=32). B rows: Wq|Wk|Wv.
__global__ __launch_bounds__(256) void gemm_qkv(const short* __restrict__ A,
        const short* __restrict__ B,
        const float* __restrict__ bq, const float* __restrict__ bk,
        const float* __restrict__ bv,
        short* __restrict__ qw, short* __restrict__ kw, short* __restrict__ vw)
{
    __shared__ short As[128 * 32];
    __shared__ short Bs[128 * 32];
    const int m0 = blockIdx.x * 128, n0 = blockIdx.y * 128;
    const int w = threadIdx.x >> 6, lane = threadIdx.x & 63;
    const int l16 = lane & 15, quad = lane >> 4;
    const int wm = w >> 1, wn = w & 1;
    const int lr = lane >> 2, lc = (lane & 3) * 8;

    floatx4 acc[4][4];
#pragma unroll
    for (int i = 0; i < 4; ++i)
#pragma unroll
        for (int j = 0; j < 4; ++j) acc[i][j] = (floatx4){0.f, 0.f, 0.f, 0.f};

    for (int kt = 0; kt < DM / 32; ++kt) {
        const int k0 = kt * 32;
        __syncthreads();
        async_copy16(A + (size_t)(m0 + w * 32 + lr) * DM + k0 + lc,      &As[w * 1024]);
        async_copy16(A + (size_t)(m0 + w * 32 + 16 + lr) * DM + k0 + lc, &As[w * 1024 + 512]);
        async_copy16(B + (size_t)(n0 + w * 32 + lr) * DM + k0 + lc,      &Bs[w * 1024]);
        async_copy16(B + (size_t)(n0 + w * 32 + 16 + lr) * DM + k0 + lc, &Bs[w * 1024 + 512]);
        __syncthreads();

        short8 af[4], bf[4];
#pragma unroll
        for (int i = 0; i < 4; ++i)
            af[i] = *(const short8*)&As[(wm * 64 + i * 16 + l16) * 32 + quad * 8];
#pragma unroll
        for (int j = 0; j < 4; ++j)
            bf[j] = *(const short8*)&Bs[(wn * 64 + j * 16 + l16) * 32 + quad * 8];
#pragma unroll
        for (int i = 0; i < 4; ++i)
#pragma unroll
            for (int j = 0; j < 4; ++j)
                acc[i][j] = __builtin_amdgcn_mfma_f32_16x16x32_bf16(af[i], bf[j], acc[i][j], 0, 0, 0);
    }

    const int m_base = m0 + wm * 64 + quad * 4;
#pragma unroll
    for (int j = 0; j < 4; ++j) {
        const int nb = n0 + wn * 64 + j * 16;
        const int t = nb >> 10;
        const int nn = (nb & 1023) + l16;
        const int h = nn >> 6, dh = nn & 63;
        const float* bias = (t == 0) ? bq : (t == 1) ? bk : bv;
        short* dst = (t == 0) ? qw : (t == 1) ? kw : vw;
        const float bvv = bias[nn];
#pragma unroll
        for (int i = 0; i < 4; ++i)
#pragma unroll
            for (int r = 0; r < 4; ++r) {
                const int m = m_base + i * 16 + r;
                const int b = m >> 11, s = m & (SEQ - 1);
                dst[(((size_t)(b * HEADS + h)) * SEQ + s) * DH + dh] = f2b(acc[i][j][r] + bvv);
            }
    }
}

// v [b,h,s,dh] -> vt [b,h,dh,s], 64x64 LDS tiles
__global__ __launch_bounds__(256) void transpose_v(const short* __restrict__ v,
                                                   short* __restrict__ vt)
{
    __shared__ short tl[64][72];
    const int st = blockIdx.x;
    const int bh = blockIdx.y;
    const int t = threadIdx.x;
    const int row = t >> 2, off = (t & 3) * 16;
    const short* vp = v + ((size_t)bh * SEQ + st * 64 + row) * DH + off;
    *(short8*)&tl[row][off]     = *(const short8*)vp;
    *(short8*)&tl[row][off + 8] = *(const short8*)(vp + 8);
    __syncthreads();
    short8 o0, o1;
#pragma unroll
    for (int j = 0; j < 8; ++j) { o0[j] = tl[off + j][row]; o1[j] = tl[off + 8 + j][row]; }
    short* op = vt + ((size_t)bh * DH + row) * SEQ + st * 64 + off;
    *(short8*)op = o0;
    *(short8*)(op + 8) = o1;
}

// Flash attention, transposed-score formulation.
// Computes S^T = K Q^T per 64-key tile: each lane owns ONE q-row (col=l16) and
// 16 key elements (4 nt x 4 reg). Softmax reductions: in-register + 2 shuffles.
// l accumulated via ones-MFMA. P stored to LDS as packed bf16x4 (A-layout).
__global__ __launch_bounds__(256) void attn_kernel(const short* __restrict__ q,
        const short* __restrict__ k, const short* __restrict__ vt,
        const float* __restrict__ mask, short* __restrict__ ctx)
{
    const int qtile = blockIdx.x;
    const int bh    = blockIdx.y;
    const int bidx  = bh >> 4;
    const int wave = threadIdx.x >> 6, lane = threadIdx.x & 63;
    const int l16 = lane & 15, quad = lane >> 4;

    __shared__ short k_lds[64][72];        // [key][dh]
    __shared__ short v_lds[64][72];        // [dh][key]
    __shared__ short p_lds[4][16][72];     // per-wave P, A-layout [qrow][key]
    __shared__ float madd_lds[SEQ];        // (1-mask)*-1e5 per key

    {   // precompute mask-add for the whole sequence (once per block)
        const int t = threadIdx.x;
        const float* mrow = mask + (size_t)bidx * SEQ;
#pragma unroll
        for (int i = 0; i < 8; ++i) {
            const int idx = t * 8 + i;
            madd_lds[idx] = (1.f - mrow[idx]) * (-100000.f);
        }
    }

    // Q fragment (B-operand layout): B[n=qrow=l16][k=dh=quad*8+j]
    const int qrow = qtile * 64 + wave * 16 + l16;
    const short* qbase = q + ((size_t)bh * SEQ + qrow) * DH;
    short8 b_q[2];
#pragma unroll
    for (int ks = 0; ks < 2; ++ks)
        b_q[ks] = *(const short8*)(qbase + ks * 32 + quad * 8);

    float m_own = -1e30f;                  // running max for row l16
    floatx4 o[4];                          // O: row=qrow(quad*4+r), col=dh(d*16+l16)
    floatx4 l_acc = (floatx4){0.f, 0.f, 0.f, 0.f};   // row-sums, same row layout as o
#pragma unroll
    for (int d = 0; d < 4; ++d) o[d] = (floatx4){0.f, 0.f, 0.f, 0.f};

    const float scale = 0.125f;            // 1/sqrt(64)
    short8 ones;
#pragma unroll
    for (int j = 0; j < 8; ++j) ones[j] = (short)0x3F80;  // bf16 1.0

    for (int kt = 0; kt < SEQ / 64; ++kt) {
        __syncthreads();                   // also covers madd_lds on first iter
        {   // stage K and V tiles
            const int t = threadIdx.x;
            const int row = t >> 2;
            const int off = (t & 3) * 16;
            const short* kp = k + ((size_t)bh * SEQ + kt * 64 + row) * DH + off;
            *(short8*)&k_lds[row][off]     = *(const short8*)kp;
            *(short8*)&k_lds[row][off + 8] = *(const short8*)(kp + 8);
            const short* vp = vt + ((size_t)bh * DH + row) * SEQ + kt * 64 + off;
            *(short8*)&v_lds[row][off]     = *(const short8*)vp;
            *(short8*)&v_lds[row][off + 8] = *(const short8*)(vp + 8);
        }
        __syncthreads();

        // S^T = K Q^T: A=K-frag (m=key), B=Q-frag (n=qrow)
        float sv[4][4];
#pragma unroll
        for (int nt = 0; nt < 4; ++nt) {
            floatx4 acc = (floatx4){0.f, 0.f, 0.f, 0.f};
#pragma unroll
            for (int ks = 0; ks < 2; ++ks) {
                short8 a = *(const short8*)&k_lds[nt * 16 + l16][ks * 32 + quad * 8];
                acc = __builtin_amdgcn_mfma_f32_16x16x32_bf16(a, b_q[ks], acc, 0, 0, 0);
            }
            const floatx4 md = *(const floatx4*)&madd_lds[kt * 64 + nt * 16 + quad * 4];
#pragma unroll
            for (int r = 0; r < 4; ++r) sv[nt][r] = acc[r] * scale + md[r];
        }

        // row max: in-register over 16, then cross-quad (xor 16, 32)
        float tm = sv[0][0];
#pragma unroll
        for (int nt = 0; nt < 4; ++nt)
#pragma unroll
            for (int r = 0; r < 4; ++r) tm = fmaxf(tm, sv[nt][r]);
        tm = fmaxf(tm, __shfl_xor(tm, 16));
        tm = fmaxf(tm, __shfl_xor(tm, 32));
        const float nm = fmaxf(m_own, tm);
        const float alpha = __expf(m_own - nm);
        m_own = nm;

        // p = exp(s - m), packed bf16x4 store into A-layout p_lds
#pragma unroll
        for (int nt = 0; nt < 4; ++nt) {
            const float p0 = __expf(sv[nt][0] - nm);
            const float p1 = __expf(sv[nt][1] - nm);
            const float p2 = __expf(sv[nt][2] - nm);
            const float p3 = __expf(sv[nt][3] - nm);
            union { __hip_bfloat162 h[2]; bf16x4 v; } u;
            u.h[0] = __float22bfloat162_rn(make_float2(p0, p1));
            u.h[1] = __float22bfloat162_rn(make_float2(p2, p3));
            *(bf16x4*)&p_lds[wave][l16][nt * 16 + quad * 4] = u.v;
        }

        // broadcast alpha to O-row layout (row = quad*4+r lives at l16=quad*4+r)
        float ab[4];
#pragma unroll
        for (int r = 0; r < 4; ++r)
            ab[r] = __shfl(alpha, (lane & 48) | (quad * 4 + r));
#pragma unroll
        for (int d = 0; d < 4; ++d)
#pragma unroll
            for (int r = 0; r < 4; ++r) o[d][r] *= ab[r];
#pragma unroll
        for (int r = 0; r < 4; ++r) l_acc[r] *= ab[r];

        // O += P V ; l += P . 1
#pragma unroll
        for (int ks2 = 0; ks2 < 2; ++ks2) {
            short8 pf = *(const short8*)&p_lds[wave][l16][ks2 * 32 + quad * 8];
#pragma unroll
            for (int d = 0; d < 4; ++d) {
                short8 vf = *(const short8*)&v_lds[d * 16 + l16][ks2 * 32 + quad * 8];
                o[d] = __builtin_amdgcn_mfma_f32_16x16x32_bf16(pf, vf, o[d], 0, 0, 0);
            }
            l_acc = __builtin_amdgcn_mfma_f32_16x16x32_bf16(pf, ones, l_acc, 0, 0, 0);
        }
    }

    // epilogue: ctx[b][s][h*64+dh] = o / l
    const int h = bh & 15, bb = bh >> 4;
    const int srow = qtile * 64 + wave * 16 + quad * 4;
    float rl[4];
#pragma unroll
    for (int r = 0; r < 4; ++r) rl[r] = 1.f / l_acc[r];
#pragma unroll
    for (int d = 0; d < 4; ++d) {
        const int dh = d * 16 + l16;
#pragma unroll
        for (int r = 0; r < 4; ++r) {
            const float val = o[d][r] * rl[r];
            ctx[((size_t)(bb * SEQ + srow + r)) * DM + h * 64 + dh] = f2b(val);
        }
    }
}

// Output GEMM + bias + residual (fp32 out into d_out).
__global__ __launch_bounds__(256) void gemm_o(const short* __restrict__ A,
        const short* __restrict__ B, const float* __restrict__ bo,
        const float* __restrict__ xin, float* __restrict__ out)
{
    __shared__ short As[128 * 32];
    __shared__ short Bs[128 * 32];
    const int m0 = blockIdx.x * 128, n0 = blockIdx.y * 128;
    const int w = threadIdx.x >> 6, lane = threadIdx.x & 63;
    const int l16 = lane & 15, quad = lane >> 4;
    const int wm = w >> 1, wn = w & 1;
    const int lr = lane >> 2, lc = (lane & 3) * 8;

    floatx4 acc[4][4];
#pragma unroll
    for (int i = 0; i < 4; ++i)
#pragma unroll
        for (int j = 0; j < 4; ++j) acc[i][j] = (floatx4){0.f, 0.f, 0.f, 0.f};

    for (int kt = 0; kt < DM / 32; ++kt) {
        const int k0 = kt * 32;
        __syncthreads();
        async_copy16(A + (size_t)(m0 + w * 32 + lr) * DM + k0 + lc,      &As[w * 1024]);
        async_copy16(A + (size_t)(m0 + w * 32 + 16 + lr) * DM + k0 + lc, &As[w * 1024 + 512]);
        async_copy16(B + (size_t)(n0 + w * 32 + lr) * DM + k0 + lc,      &Bs[w * 1024]);
        async_copy16(B + (size_t)(n0 + w * 32 + 16 + lr) * DM + k0 + lc, &Bs[w * 1024 + 512]);
        __syncthreads();

        short8 af[4], bf[4];
#pragma unroll
        for (int i = 0; i < 4; ++i)
            af[i] = *(const short8*)&As[(wm * 64 + i * 16 + l16) * 32 + quad * 8];
#pragma unroll
        for (int j = 0; j < 4; ++j)
            bf[j] = *(const short8*)&Bs[(wn * 64 + j * 16 + l16) * 32 + quad * 8];
#pragma unroll
        for (int i = 0; i < 4; ++i)
#pragma unroll
            for (int j = 0; j < 4; ++j)
                acc[i][j] = __builtin_amdgcn_mfma_f32_16x16x32_bf16(af[i], bf[j], acc[i][j], 0, 0, 0);
    }

    const int m_base = m0 + wm * 64 + quad * 4;
#pragma unroll
    for (int j = 0; j < 4; ++j) {
        const int n = n0 + wn * 64 + j * 16 + l16;
        const float bvv = bo[n];
#pragma unroll
        for (int i = 0; i < 4; ++i)
#pragma unroll
            for (int r = 0; r < 4; ++r) {
                const int m = m_base + i * 16 + r;
                const size_t idx = (size_t)m * DM + n;
                out[idx] = acc[i][j][r] + bvv + xin[idx];
            }
    }
}

__global__ __launch_bounds__(256) void ln_kernel(float* __restrict__ y,
        const float* __restrict__ gamma, const float* __restrict__ beta)
{
    const int row = blockIdx.x;
    const int t = threadIdx.x;
    const int wave = t >> 6, lane = t & 63;
    const floatx4 v = ((const floatx4*)(y + (size_t)row * DM))[t];
    float s  = v.x + v.y + v.z + v.w;
    float q2 = v.x * v.x + v.y * v.y + v.z * v.z + v.w * v.w;
#pragma unroll
    for (int off = 1; off < 64; off <<= 1) {
        s  += __shfl_xor(s, off);
        q2 += __shfl_xor(q2, off);
    }
    __shared__ float rs[4], rq[4];
    if (lane == 0) { rs[wave] = s; rq[wave] = q2; }
    __syncthreads();
    const float S  = rs[0] + rs[1] + rs[2] + rs[3];
    const float Q2 = rq[0] + rq[1] + rq[2] + rq[3];
    const float mu = S * (1.f / DM);
    float var = Q2 * (1.f / DM) - mu * mu;
    var = fmaxf(var, 0.f);
    const float rstd = rsqrtf(var + 1e-12f);
    const floatx4 g = ((const floatx4*)gamma)[t];
    const floatx4 bt = ((const floatx4*)beta)[t];
    floatx4 o;
    o.x = (v.x - mu) * rstd * g.x + bt.x;
    o.y = (v.y - mu) * rstd * g.y + bt.y;
    o.z = (v.z - mu) * rstd * g.z + bt.z;
    o.w = (v.w - mu) * rstd * g.w + bt.w;
    ((floatx4*)(y + (size_t)row * DM))[t] = o;
}

extern "C" void kernel_launch(void* const* d_in, const int* in_sizes, int n_in,
                              void* d_out, int out_size, void* d_ws, size_t ws_size,
                              hipStream_t stream) {
    const float* x     = (const float*)d_in[0];
    const float* mask  = (const float*)d_in[1];
    const float* Wq    = (const float*)d_in[2];
    const float* bq    = (const float*)d_in[3];
    const float* Wk    = (const float*)d_in[4];
    const float* bk    = (const float*)d_in[5];
    const float* Wv    = (const float*)d_in[6];
    const float* bv    = (const float*)d_in[7];
    const float* Wo    = (const float*)d_in[8];
    const float* bo    = (const float*)d_in[9];
    const float* gamma = (const float*)d_in[10];
    const float* beta  = (const float*)d_in[11];
    float* out = (float*)d_out;

    const size_t NTOK = (size_t)BATCH * SEQ * DM;       // 4M
    const size_t WSZ  = (size_t)DM * DM;                // 1M
    short* xb   = (short*)d_ws;          // 4M
    short* wqkv = xb + NTOK;             // 3M
    short* wob  = wqkv + 3 * WSZ;        // 1M
    short* qw   = wob + WSZ;             // 4M
    short* kw   = qw + NTOK;             // 4M
    short* vw   = kw + NTOK;             // 4M (aliased as ctx after transpose)
    short* vtw  = vw + NTOK;             // 4M
    short* ctxw = vw;

    dim3 blk(256);
    cvt_all<<<dim3(8192), blk, 0, stream>>>(x, Wq, Wk, Wv, Wo, xb, wqkv, wob);
    gemm_qkv<<<dim3(32, 24), blk, 0, stream>>>(xb, wqkv, bq, bk, bv, qw, kw, vw);
    transpose_v<<<dim3(SEQ / 64, BATCH * HEADS), blk, 0, stream>>>(vw, vtw);
    attn_kernel<<<dim3(SEQ / 64, BATCH * HEADS), blk, 0, stream>>>(qw, kw, vtw, mask, ctxw);
    gemm_o<<<dim3(32, 8), blk, 0, stream>>>(ctxw, wob, bo, x, out);
    ln_kernel<<<BATCH * SEQ, blk, 0, stream>>>(out, gamma, beta);
}

// Round 6
// 232.127 us; speedup vs baseline: 3.3675x; 1.0590x over previous
//
#include <hip/hip_runtime.h>
#include <hip/hip_bf16.h>

#define DM   1024
#define HEADS 16
#define DH    64
#define SEQ  2048
#define BATCH   2

typedef __attribute__((ext_vector_type(8))) short short8;
typedef __attribute__((ext_vector_type(4))) short bf16x4;
typedef __attribute__((ext_vector_type(4))) float floatx4;

__device__ __forceinline__ short f2b(float f) {
    union { float f; unsigned u; } v; v.f = f;
    unsigned r = v.u + 0x7FFFu + ((v.u >> 16) & 1u);
    return (short)(r >> 16);
}

__device__ __forceinline__ void async_copy16(const short* gsrc, short* ldst) {
    __builtin_amdgcn_global_load_lds(
        (const __attribute__((address_space(1))) void*)gsrc,
        (__attribute__((address_space(3))) void*)ldst,
        16, 0, 0);
}

// Fused fp32->bf16 conversion of x, Wq, Wk, Wv, Wo in one launch.
__global__ __launch_bounds__(256) void cvt_all(const float* __restrict__ x,
        const float* __restrict__ wq, const float* __restrict__ wk,
        const float* __restrict__ wv, const float* __restrict__ wo,
        short* __restrict__ xb, short* __restrict__ wqkv, short* __restrict__ wob)
{
    const int b = blockIdx.x;
    const float* src; short* dst; int idx;
    if (b < 4096)      { src = x;  dst = xb;                idx = b; }
    else if (b < 5120) { src = wq; dst = wqkv;              idx = b - 4096; }
    else if (b < 6144) { src = wk; dst = wqkv + (1 << 20);  idx = b - 5120; }
    else if (b < 7168) { src = wv; dst = wqkv + (2 << 20);  idx = b - 6144; }
    else               { src = wo; dst = wob;               idx = b - 7168; }
    const int i = idx * 256 + threadIdx.x;
    floatx4 v = ((const floatx4*)src)[i];
    bf16x4 o;
    o.x = f2b(v.x); o.y = f2b(v.y); o.z = f2b(v.z); o.w = f2b(v.w);
    ((bf16x4*)dst)[i] = o;
}

// Fused QKV GEMM (m97 structure, 128x128 tile, BK=32). B rows: Wq|Wk|Wv.
// Q is pre-scaled by 1/sqrt(DH)=0.125 so attention needs no score scaling.
__global__ __launch_bounds__(256) void gemm_qkv(const short* __restrict__ A,
        const short* __restrict__ B,
        const float* __restrict__ bq, const float* __restrict__ bk,
        const float* __restrict__ bv,
        short* __restrict__ qw, short* __restrict__ kw, short* __restrict__ vw)
{
    __shared__ short As[128 * 32];
    __shared__ short Bs[128 * 32];
    const int m0 = blockIdx.x * 128, n0 = blockIdx.y * 128;
    const int w = threadIdx.x >> 6, lane = threadIdx.x & 63;
    const int l16 = lane & 15, quad = lane >> 4;
    const int wm = w >> 1, wn = w & 1;
    const int lr = lane >> 2, lc = (lane & 3) * 8;

    floatx4 acc[4][4];
#pragma unroll
    for (int i = 0; i < 4; ++i)
#pragma unroll
        for (int j = 0; j < 4; ++j) acc[i][j] = (floatx4){0.f, 0.f, 0.f, 0.f};

    for (int kt = 0; kt < DM / 32; ++kt) {
        const int k0 = kt * 32;
        __syncthreads();
        async_copy16(A + (size_t)(m0 + w * 32 + lr) * DM + k0 + lc,      &As[w * 1024]);
        async_copy16(A + (size_t)(m0 + w * 32 + 16 + lr) * DM + k0 + lc, &As[w * 1024 + 512]);
        async_copy16(B + (size_t)(n0 + w * 32 + lr) * DM + k0 + lc,      &Bs[w * 1024]);
        async_copy16(B + (size_t)(n0 + w * 32 + 16 + lr) * DM + k0 + lc, &Bs[w * 1024 + 512]);
        __syncthreads();

        short8 af[4], bf[4];
#pragma unroll
        for (int i = 0; i < 4; ++i)
            af[i] = *(const short8*)&As[(wm * 64 + i * 16 + l16) * 32 + quad * 8];
#pragma unroll
        for (int j = 0; j < 4; ++j)
            bf[j] = *(const short8*)&Bs[(wn * 64 + j * 16 + l16) * 32 + quad * 8];
#pragma unroll
        for (int i = 0; i < 4; ++i)
#pragma unroll
            for (int j = 0; j < 4; ++j)
                acc[i][j] = __builtin_amdgcn_mfma_f32_16x16x32_bf16(af[i], bf[j], acc[i][j], 0, 0, 0);
    }

    const int m_base = m0 + wm * 64 + quad * 4;
#pragma unroll
    for (int j = 0; j < 4; ++j) {
        const int nb = n0 + wn * 64 + j * 16;
        const int t = nb >> 10;
        const int nn = (nb & 1023) + l16;
        const int h = nn >> 6, dh = nn & 63;
        const float* bias = (t == 0) ? bq : (t == 1) ? bk : bv;
        short* dst = (t == 0) ? qw : (t == 1) ? kw : vw;
        const float mulf = (t == 0) ? 0.125f : 1.0f;   // fold 1/sqrt(DH) into Q
        const float bvv = bias[nn];
#pragma unroll
        for (int i = 0; i < 4; ++i)
#pragma unroll
            for (int r = 0; r < 4; ++r) {
                const int m = m_base + i * 16 + r;
                const int b = m >> 11, s = m & (SEQ - 1);
                dst[(((size_t)(b * HEADS + h)) * SEQ + s) * DH + dh] =
                    f2b((acc[i][j][r] + bvv) * mulf);
            }
    }
}

// v [b,h,s,dh] -> vt [b,h,dh,s], 64x64 LDS tiles
__global__ __launch_bounds__(256) void transpose_v(const short* __restrict__ v,
                                                   short* __restrict__ vt)
{
    __shared__ short tl[64][72];
    const int st = blockIdx.x;
    const int bh = blockIdx.y;
    const int t = threadIdx.x;
    const int row = t >> 2, off = (t & 3) * 16;
    const short* vp = v + ((size_t)bh * SEQ + st * 64 + row) * DH + off;
    *(short8*)&tl[row][off]     = *(const short8*)vp;
    *(short8*)&tl[row][off + 8] = *(const short8*)(vp + 8);
    __syncthreads();
    short8 o0, o1;
#pragma unroll
    for (int j = 0; j < 8; ++j) { o0[j] = tl[off + j][row]; o1[j] = tl[off + 8 + j][row]; }
    short* op = vt + ((size_t)bh * DH + row) * SEQ + st * 64 + off;
    *(short8*)op = o0;
    *(short8*)(op + 8) = o1;
}

// Flash attention, transposed-score formulation, xor-swizzled packed LDS.
// LDS tiles stored as 16B chunks with chunk' = chunk ^ (row&7): all fragment
// reads are 2-way (free); staging is direct global_load_lds (no VGPR trip).
// Q pre-scaled by 0.125; mask term injected as MFMA C-init.
__global__ __launch_bounds__(256) void attn_kernel(const short* __restrict__ q,
        const short* __restrict__ k, const short* __restrict__ vt,
        const float* __restrict__ mask, short* __restrict__ ctx)
{
    const int qtile = blockIdx.x;
    const int bh    = blockIdx.y;
    const int bidx  = bh >> 4;
    const int wave = threadIdx.x >> 6, lane = threadIdx.x & 63;
    const int l16 = lane & 15, quad = lane >> 4;
    const int lx = l16 & 7;

    __shared__ short k_lds[64 * 64];       // [key][dh] packed+swizzled
    __shared__ short v_lds[64 * 64];       // [dh][key] packed+swizzled
    __shared__ short p_lds[4][16 * 64];    // per-wave P [qrow][key] swizzled
    __shared__ float madd_lds[SEQ];        // (1-mask)*-1e5 per key

    {   // precompute mask-add once per block
        const int t = threadIdx.x;
        const float* mrow = mask + (size_t)bidx * SEQ;
#pragma unroll
        for (int i = 0; i < 8; ++i) {
            const int idx = t * 8 + i;
            madd_lds[idx] = (1.f - mrow[idx]) * (-100000.f);
        }
    }

    // Q fragment (B-operand): B[n=qrow=l16][k=dh=quad*8+j]
    const int qrow = qtile * 64 + wave * 16 + l16;
    const short* qbase = q + ((size_t)bh * SEQ + qrow) * DH;
    short8 b_q[2];
#pragma unroll
    for (int ks = 0; ks < 2; ++ks)
        b_q[ks] = *(const short8*)(qbase + ks * 32 + quad * 8);

    float m_own = -1e30f;
    floatx4 o[4];
    floatx4 l_acc = (floatx4){0.f, 0.f, 0.f, 0.f};
#pragma unroll
    for (int d = 0; d < 4; ++d) o[d] = (floatx4){0.f, 0.f, 0.f, 0.f};

    short8 ones;
#pragma unroll
    for (int j = 0; j < 8; ++j) ones[j] = (short)0x3F80;  // bf16 1.0

    const short* kbase0 = k  + (size_t)bh * SEQ * DH;
    const short* vbase0 = vt + (size_t)bh * DH * SEQ;

    for (int kt = 0; kt < SEQ / 64; ++kt) {
        __syncthreads();                   // prev tile fully consumed (also madd init)
        {   // stage K,V via global_load_lds; slot -> global chunk xor-permuted
            const short* kbase = kbase0 + (size_t)(kt * 64) * DH;
            const short* vbase = vbase0 + kt * 64;
#pragma unroll
            for (int i = 0; i < 2; ++i) {
                const int slot = i * 256 + wave * 64 + lane;
                const int row = slot >> 3, c = slot & 7;
                const int g = c ^ (row & 7);
                async_copy16(kbase + row * DH  + g * 8, &k_lds[(i * 256 + wave * 64) * 8]);
                async_copy16(vbase + (size_t)row * SEQ + g * 8, &v_lds[(i * 256 + wave * 64) * 8]);
            }
        }
        __syncthreads();                   // compiler emits vmcnt(0) before barrier

        // S^T = K Q^T, C initialized with mask-add (rows=key=quad*4+r)
        float sv[4][4];
#pragma unroll
        for (int nt = 0; nt < 4; ++nt) {
            floatx4 acc = *(const floatx4*)&madd_lds[kt * 64 + nt * 16 + quad * 4];
#pragma unroll
            for (int ks = 0; ks < 2; ++ks) {
                short8 a = *(const short8*)
                    &k_lds[(nt * 16 + l16) * 64 + (((ks * 4 + quad) ^ lx) * 8)];
                acc = __builtin_amdgcn_mfma_f32_16x16x32_bf16(a, b_q[ks], acc, 0, 0, 0);
            }
#pragma unroll
            for (int r = 0; r < 4; ++r) sv[nt][r] = acc[r];
        }

        // row max (per qrow=l16): in-register 16, then cross-quad
        float tm = sv[0][0];
#pragma unroll
        for (int nt = 0; nt < 4; ++nt)
#pragma unroll
            for (int r = 0; r < 4; ++r) tm = fmaxf(tm, sv[nt][r]);
        tm = fmaxf(tm, __shfl_xor(tm, 16));
        tm = fmaxf(tm, __shfl_xor(tm, 32));
        const int upd = __any(tm > m_own);
        const float nm = fmaxf(m_own, tm);

        // p = exp(s - m), packed bf16x4 store (swizzled)
#pragma unroll
        for (int nt = 0; nt < 4; ++nt) {
            const float p0 = __expf(sv[nt][0] - nm);
            const float p1 = __expf(sv[nt][1] - nm);
            const float p2 = __expf(sv[nt][2] - nm);
            const float p3 = __expf(sv[nt][3] - nm);
            union { __hip_bfloat162 h[2]; bf16x4 v; } u;
            u.h[0] = __float22bfloat162_rn(make_float2(p0, p1));
            u.h[1] = __float22bfloat162_rn(make_float2(p2, p3));
            *(bf16x4*)&p_lds[wave][l16 * 64 +
                (((nt * 2 + (quad >> 1)) ^ lx) * 8) + (quad & 1) * 4] = u.v;
        }

        if (upd) {   // wave-uniform: some row's max increased -> rescale
            const float alpha = __expf(m_own - nm);
            float ab[4];
#pragma unroll
            for (int r = 0; r < 4; ++r)
                ab[r] = __shfl(alpha, (lane & 48) | (quad * 4 + r));
#pragma unroll
            for (int d = 0; d < 4; ++d)
#pragma unroll
                for (int r = 0; r < 4; ++r) o[d][r] *= ab[r];
#pragma unroll
            for (int r = 0; r < 4; ++r) l_acc[r] *= ab[r];
        }
        m_own = nm;

        // O += P V ; l += P . 1
#pragma unroll
        for (int ks2 = 0; ks2 < 2; ++ks2) {
            short8 pf = *(const short8*)
                &p_lds[wave][l16 * 64 + (((ks2 * 4 + quad) ^ lx) * 8)];
#pragma unroll
            for (int d = 0; d < 4; ++d) {
                short8 vf = *(const short8*)
                    &v_lds[(d * 16 + l16) * 64 + (((ks2 * 4 + quad) ^ lx) * 8)];
                o[d] = __builtin_amdgcn_mfma_f32_16x16x32_bf16(pf, vf, o[d], 0, 0, 0);
            }
            l_acc = __builtin_amdgcn_mfma_f32_16x16x32_bf16(pf, ones, l_acc, 0, 0, 0);
        }
    }

    // epilogue: ctx[b][s][h*64+dh] = o / l
    const int h = bh & 15, bb = bh >> 4;
    const int srow = qtile * 64 + wave * 16 + quad * 4;
    float rl[4];
#pragma unroll
    for (int r = 0; r < 4; ++r) rl[r] = 1.f / l_acc[r];
#pragma unroll
    for (int d = 0; d < 4; ++d) {
        const int dh = d * 16 + l16;
#pragma unroll
        for (int r = 0; r < 4; ++r) {
            const float val = o[d][r] * rl[r];
            ctx[((size_t)(bb * SEQ + srow + r)) * DM + h * 64 + dh] = f2b(val);
        }
    }
}

// Output GEMM + bias + residual (fp32 out into d_out).
__global__ __launch_bounds__(256) void gemm_o(const short* __restrict__ A,
        const short* __restrict__ B, const float* __restrict__ bo,
        const float* __restrict__ xin, float* __restrict__ out)
{
    __shared__ short As[128 * 32];
    __shared__ short Bs[128 * 32];
    const int m0 = blockIdx.x * 128, n0 = blockIdx.y * 128;
    const int w = threadIdx.x >> 6, lane = threadIdx.x & 63;
    const int l16 = lane & 15, quad = lane >> 4;
    const int wm = w >> 1, wn = w & 1;
    const int lr = lane >> 2, lc = (lane & 3) * 8;

    floatx4 acc[4][4];
#pragma unroll
    for (int i = 0; i < 4; ++i)
#pragma unroll
        for (int j = 0; j < 4; ++j) acc[i][j] = (floatx4){0.f, 0.f, 0.f, 0.f};

    for (int kt = 0; kt < DM / 32; ++kt) {
        const int k0 = kt * 32;
        __syncthreads();
        async_copy16(A + (size_t)(m0 + w * 32 + lr) * DM + k0 + lc,      &As[w * 1024]);
        async_copy16(A + (size_t)(m0 + w * 32 + 16 + lr) * DM + k0 + lc, &As[w * 1024 + 512]);
        async_copy16(B + (size_t)(n0 + w * 32 + lr) * DM + k0 + lc,      &Bs[w * 1024]);
        async_copy16(B + (size_t)(n0 + w * 32 + 16 + lr) * DM + k0 + lc, &Bs[w * 1024 + 512]);
        __syncthreads();

        short8 af[4], bf[4];
#pragma unroll
        for (int i = 0; i < 4; ++i)
            af[i] = *(const short8*)&As[(wm * 64 + i * 16 + l16) * 32 + quad * 8];
#pragma unroll
        for (int j = 0; j < 4; ++j)
            bf[j] = *(const short8*)&Bs[(wn * 64 + j * 16 + l16) * 32 + quad * 8];
#pragma unroll
        for (int i = 0; i < 4; ++i)
#pragma unroll
            for (int j = 0; j < 4; ++j)
                acc[i][j] = __builtin_amdgcn_mfma_f32_16x16x32_bf16(af[i], bf[j], acc[i][j], 0, 0, 0);
    }

    const int m_base = m0 + wm * 64 + quad * 4;
#pragma unroll
    for (int j = 0; j < 4; ++j) {
        const int n = n0 + wn * 64 + j * 16 + l16;
        const float bvv = bo[n];
#pragma unroll
        for (int i = 0; i < 4; ++i)
#pragma unroll
            for (int r = 0; r < 4; ++r) {
                const int m = m_base + i * 16 + r;
                const size_t idx = (size_t)m * DM + n;
                out[idx] = acc[i][j][r] + bvv + xin[idx];
            }
    }
}

__global__ __launch_bounds__(256) void ln_kernel(float* __restrict__ y,
        const float* __restrict__ gamma, const float* __restrict__ beta)
{
    const int row = blockIdx.x;
    const int t = threadIdx.x;
    const int wave = t >> 6, lane = t & 63;
    const floatx4 v = ((const floatx4*)(y + (size_t)row * DM))[t];
    float s  = v.x + v.y + v.z + v.w;
    float q2 = v.x * v.x + v.y * v.y + v.z * v.z + v.w * v.w;
#pragma unroll
    for (int off = 1; off < 64; off <<= 1) {
        s  += __shfl_xor(s, off);
        q2 += __shfl_xor(q2, off);
    }
    __shared__ float rs[4], rq[4];
    if (lane == 0) { rs[wave] = s; rq[wave] = q2; }
    __syncthreads();
    const float S  = rs[0] + rs[1] + rs[2] + rs[3];
    const float Q2 = rq[0] + rq[1] + rq[2] + rq[3];
    const float mu = S * (1.f / DM);
    float var = Q2 * (1.f / DM) - mu * mu;
    var = fmaxf(var, 0.f);
    const float rstd = rsqrtf(var + 1e-12f);
    const floatx4 g = ((const floatx4*)gamma)[t];
    const floatx4 bt = ((const floatx4*)beta)[t];
    floatx4 o;
    o.x = (v.x - mu) * rstd * g.x + bt.x;
    o.y = (v.y - mu) * rstd * g.y + bt.y;
    o.z = (v.z - mu) * rstd * g.z + bt.z;
    o.w = (v.w - mu) * rstd * g.w + bt.w;
    ((floatx4*)(y + (size_t)row * DM))[t] = o;
}

extern "C" void kernel_launch(void* const* d_in, const int* in_sizes, int n_in,
                              void* d_out, int out_size, void* d_ws, size_t ws_size,
                              hipStream_t stream) {
    const float* x     = (const float*)d_in[0];
    const float* mask  = (const float*)d_in[1];
    const float* Wq    = (const float*)d_in[2];
    const float* bq    = (const float*)d_in[3];
    const float* Wk    = (const float*)d_in[4];
    const float* bk    = (const float*)d_in[5];
    const float* Wv    = (const float*)d_in[6];
    const float* bv    = (const float*)d_in[7];
    const float* Wo    = (const float*)d_in[8];
    const float* bo    = (const float*)d_in[9];
    const float* gamma = (const float*)d_in[10];
    const float* beta  = (const float*)d_in[11];
    float* out = (float*)d_out;

    const size_t NTOK = (size_t)BATCH * SEQ * DM;       // 4M
    const size_t WSZ  = (size_t)DM * DM;                // 1M
    short* xb   = (short*)d_ws;          // 4M
    short* wqkv = xb + NTOK;             // 3M
    short* wob  = wqkv + 3 * WSZ;        // 1M
    short* qw   = wob + WSZ;             // 4M
    short* kw   = qw + NTOK;             // 4M
    short* vw   = kw + NTOK;             // 4M (aliased as ctx after transpose)
    short* vtw  = vw + NTOK;             // 4M
    short* ctxw = vw;

    dim3 blk(256);
    cvt_all<<<dim3(8192), blk, 0, stream>>>(x, Wq, Wk, Wv, Wo, xb, wqkv, wob);
    gemm_qkv<<<dim3(32, 24), blk, 0, stream>>>(xb, wqkv, bq, bk, bv, qw, kw, vw);
    transpose_v<<<dim3(SEQ / 64, BATCH * HEADS), blk, 0, stream>>>(vw, vtw);
    attn_kernel<<<dim3(SEQ / 64, BATCH * HEADS), blk, 0, stream>>>(qw, kw, vtw, mask, ctxw);
    gemm_o<<<dim3(32, 8), blk, 0, stream>>>(ctxw, wob, bo, x, out);
    ln_kernel<<<BATCH * SEQ, blk, 0, stream>>>(out, gamma, beta);
}